// Round 7
// baseline (3764.017 us; speedup 1.0000x reference)
//
#include <hip/hip_runtime.h>
#include <math.h>

#define HEADS 4
#define HC 512          // HEADS * OUT_CH
#define CIN 128
#define COUT 128
#define NEG_SLOPE 0.2f

typedef __attribute__((ext_vector_type(8))) short bf16x8;
typedef __attribute__((ext_vector_type(4))) float f32x4;

union BF8 { unsigned short u[8]; unsigned u32[4]; bf16x8 v; };

// ---- float <-> ordered-uint encoding for atomic max on floats ----
__device__ __forceinline__ unsigned enc_f(float f){
  unsigned u = __float_as_uint(f);
  return (u & 0x80000000u) ? ~u : (u | 0x80000000u);
}
__device__ __forceinline__ float dec_f(unsigned k){
  unsigned u = (k & 0x80000000u) ? (k & 0x7fffffffu) : ~k;
  return __uint_as_float(u);
}
#define ENC_NEGINF 0x007FFFFFu   // enc(-inf)

__device__ __forceinline__ unsigned short f2bf(float f){
  unsigned u = __float_as_uint(f);
  unsigned r = u + 0x7fffu + ((u >> 16) & 1u);   // RNE
  return (unsigned short)(r >> 16);
}
__device__ __forceinline__ float bf2f(unsigned short s){
  return __uint_as_float((unsigned)s << 16);
}

// split-4+16 permutation: slot-index m=8g+i <-> spec-k 4g+(i&3)+16*(i>>2)
__device__ __forceinline__ int d_pi(int k){
  return k<16 ? 8*(k>>2)+(k&3) : 8*((k-16)>>2)+4+((k-16)&3);
}
__device__ __forceinline__ int d_pinv(int m){
  return (m&7)<4 ? 4*(m>>3)+(m&3) : 16+4*(m>>3)+(m&3);
}

// ---- runtime MFMA layout probe: writes flag 0..4 ----
// 0: consistent consecutive-8 loading gives correct D with C-map (col=l&15,row=g*4+reg)
// 1: result is the TRANSPOSE of that (C-map swapped / operand-arg swap)
// 2: B operand uses split-4+16 k-order (A consecutive)
// 3: A operand uses split-4+16 k-order (B consecutive)
// 4: none matched -> use VALU fallback
__global__ void k_probe(int* __restrict__ flag){
  int l = threadIdx.x & 63;
  int g = l>>4, c = l&15;
  bool e0=true,e1=true,e2=true,e3=true;
  for (int pr=0; pr<2; ++pr){
    BF8 A, B;
    #pragma unroll
    for (int i=0;i<8;++i){
      int k = 8*g + i;
      A.u[i] = f2bf((k == c + pr*16) ? 1.f : 0.f);
      bool inw = pr ? (k>=16) : (k<16);
      B.u[i] = f2bf(inw ? (float)((k - pr*16)*16 + c) : 0.f);
    }
    f32x4 acc = (f32x4){0.f,0.f,0.f,0.f};
    acc = __builtin_amdgcn_mfma_f32_16x16x32_bf16(A.v, B.v, acc, 0, 0, 0);
    #pragma unroll
    for (int j=0;j<4;++j){
      float got = acc[j];
      int rho = g*4 + j;
      int sr  = rho + pr*16;     // k-index of the delta row this D-row should pick
      // window formula: value of B[sel][c] as constructed this probe
      auto wf = [&](int sel)->float{
        if (pr==0) return sel<16  ? (float)(sel*16 + c)      : 0.f;
        else       return sel>=16 ? (float)((sel-16)*16 + c) : 0.f;
      };
      e0 &= (got == wf(sr));
      e1 &= (got == (float)(c*16 + rho));
      e2 &= (got == wf(d_pi(sr)));
      e3 &= (got == wf(d_pinv(sr)));
    }
  }
  e0 = __all(e0 ? 1 : 0); e1 = __all(e1 ? 1 : 0);
  e2 = __all(e2 ? 1 : 0); e3 = __all(e3 ? 1 : 0);
  if (l == 0) *flag = e0 ? 0 : (e1 ? 1 : (e2 ? 2 : (e3 ? 3 : 4)));
}

// ---- init m=-inf, s=0, hist=0 ----
__global__ void k_init(unsigned* __restrict__ m, float* __restrict__ s,
                       int* __restrict__ hist, int n){
  int i = blockIdx.x*blockDim.x + threadIdx.x;
  if (i < 4*n){ m[i] = ENC_NEGINF; s[i] = 0.f; }
  if (i < n) hist[i] = 0;
}

// ---- prep: proj_w -> BT[c(128)][k(512)] bf16 ----
__global__ void k_prep(const float* __restrict__ pw,
                       unsigned short* __restrict__ BT){
  int i = blockIdx.x*blockDim.x + threadIdx.x;
  if (i < 65536){
    BT[i] = f2bf(pw[(i&511)*COUT + (i>>9)]);   // BT[c*512+k] = proj_w[k][c]
  }
}

// ---- GEMM1 (fp32 VALU, proven): h2 = bf16(x @ lin_w); fused asrc/adst ----
__global__ __launch_bounds__(64) void k_lin(const float* __restrict__ x,
                                            const float* __restrict__ w,
                                            const float* __restrict__ as_w,
                                            const float* __restrict__ ad_w,
                                            unsigned short* __restrict__ h2,
                                            float* __restrict__ asrc,
                                            float* __restrict__ adst, int n){
  __shared__ float xs[8*CIN];
  int row0 = blockIdx.x*8;
  int tid  = threadIdx.x;
  int rows = n - row0; if (rows > 8) rows = 8;
  const float4* x4 = (const float4*)(x + (size_t)row0*CIN);
  float4* xs4 = (float4*)xs;
  #pragma unroll
  for (int i=0;i<4;++i){
    int f = i*64 + tid;            // 0..255, row = f>>5
    float4 v = (f>>5) < rows ? x4[f] : make_float4(0,0,0,0);
    xs4[f] = v;
  }
  __syncthreads();
  float acc[8][8];
  #pragma unroll
  for (int r=0;r<8;++r)
    #pragma unroll
    for (int c=0;c<8;++c) acc[r][c] = 0.f;
  int c0 = tid*8;
  for (int k=0;k<CIN;k+=4){
    float4 xv[8];
    #pragma unroll
    for (int r=0;r<8;++r) xv[r] = *(const float4*)&xs[r*CIN+k];
    #pragma unroll
    for (int kk=0;kk<4;++kk){
      float4 w0 = *(const float4*)&w[(size_t)(k+kk)*HC + c0];
      float4 w1 = *(const float4*)&w[(size_t)(k+kk)*HC + c0 + 4];
      float wv[8] = {w0.x,w0.y,w0.z,w0.w,w1.x,w1.y,w1.z,w1.w};
      #pragma unroll
      for (int r=0;r<8;++r){
        float a = ((const float*)&xv[r])[kk];
        #pragma unroll
        for (int c=0;c<8;++c) acc[r][c] = fmaf(a, wv[c], acc[r][c]);
      }
    }
  }
  int head = tid >> 4;
  int cc   = (tid & 15) * 8;
  float asv[8], adv[8];
  #pragma unroll
  for (int c=0;c<8;++c){ asv[c] = as_w[head*COUT + cc + c]; adv[c] = ad_w[head*COUT + cc + c]; }
  #pragma unroll
  for (int r=0;r<8;++r){
    if (r >= rows) break;
    unsigned short vs[8];
    #pragma unroll
    for (int c=0;c<8;++c) vs[c] = f2bf(acc[r][c]);
    *(uint4*)&h2[(size_t)(row0+r)*HC + c0] = *(uint4*)vs;
    float ps = 0.f, pd = 0.f;
    #pragma unroll
    for (int c=0;c<8;++c){ ps = fmaf(acc[r][c], asv[c], ps); pd = fmaf(acc[r][c], adv[c], pd); }
    #pragma unroll
    for (int off=1; off<16; off<<=1){ ps += __shfl_xor(ps, off); pd += __shfl_xor(pd, off); }
    if ((tid & 15) == 0){
      asrc[(size_t)(row0+r)*4 + head] = ps;
      adst[(size_t)(row0+r)*4 + head] = pd;
    }
  }
}

// ---- edge logits + dst histogram ----
__global__ void k_logits(const int* __restrict__ ei, const float* __restrict__ asrc,
                         const float* __restrict__ adst, float* __restrict__ eo,
                         unsigned* __restrict__ m, int* __restrict__ hist,
                         int E, int ET){
  int e = blockIdx.x*blockDim.x + threadIdx.x;
  if (e >= ET) return;
  int sN = e < E ? ei[e]   : e-E;
  int dN = e < E ? ei[E+e] : e-E;
  atomicAdd(&hist[dN], 1);
  #pragma unroll
  for (int hh=0; hh<4; ++hh){
    float lg = asrc[sN*4+hh] + adst[dN*4+hh];
    lg = lg > 0.f ? lg : NEG_SLOPE*lg;
    eo[(size_t)e*4+hh] = lg;
    atomicMax(&m[dN*4+hh], enc_f(lg));
  }
}

// ---- 3-phase exclusive scan (tile = 4096) ----
#define STILE 4096
__global__ __launch_bounds__(1024) void k_scan1(const int* __restrict__ in,
                                                int* __restrict__ out,
                                                int* __restrict__ tsum, int n){
  __shared__ int ls[1024];
  int b = blockIdx.x, tid = threadIdx.x;
  int base = b*STILE + tid*4;
  int v[4];
  #pragma unroll
  for (int i=0;i<4;++i){ int idx=base+i; v[i] = idx<n ? in[idx] : 0; }
  int run = v[0]+v[1]+v[2]+v[3];
  ls[tid]=run; __syncthreads();
  for (int off=1; off<1024; off<<=1){
    int t = (tid>=off) ? ls[tid-off] : 0;
    __syncthreads();
    ls[tid]+=t; __syncthreads();
  }
  int excl = ls[tid]-run;
  int sv[4]; sv[0]=excl+v[0]; sv[1]=sv[0]+v[1]; sv[2]=sv[1]+v[2]; sv[3]=sv[2]+v[3];
  #pragma unroll
  for (int i=0;i<4;++i){ int idx=base+i; if (idx<n) out[idx]=sv[i]; }
  if (tid==1023) tsum[b]=ls[1023];
}
__global__ void k_scan2(int* __restrict__ tsum, int T){
  if (threadIdx.x==0 && blockIdx.x==0){
    int off=0;
    for (int t=0;t<T;++t){ int v=tsum[t]; tsum[t]=off; off+=v; }
  }
}
__global__ void k_scan3(const int* __restrict__ scn, const int* __restrict__ toff,
                        int* __restrict__ rowptr, int* __restrict__ cur, int n){
  int i = blockIdx.x*blockDim.x + threadIdx.x;
  if (i<n){
    rowptr[i+1] = scn[i] + toff[i/STILE];
    cur[i] = (i==0) ? 0 : scn[i-1] + toff[(i-1)/STILE];
  }
  if (i==0) rowptr[0] = 0;
}

// ---- exp(e - m[dst]); atomic segment sum ----
__global__ void k_expsum(const int* __restrict__ ei, float* __restrict__ eo,
                         const unsigned* __restrict__ m, float* __restrict__ s,
                         int E, int ET){
  int e = blockIdx.x*blockDim.x + threadIdx.x;
  if (e >= ET) return;
  int dN = e < E ? ei[E+e] : e-E;
  #pragma unroll
  for (int hh=0; hh<4; ++hh){
    float ex = expf(eo[(size_t)e*4+hh] - dec_f(m[dN*4+hh]));
    eo[(size_t)e*4+hh] = ex;
    atomicAdd(&s[dN*4+hh], ex);
  }
}

// ---- scatter: pre-resolved CSR payload (src id + normalized alpha4) ----
__global__ void k_scatter(const int* __restrict__ ei, int* __restrict__ cur,
                          const float* __restrict__ eo, const float* __restrict__ ssum,
                          int* __restrict__ srcs, float* __restrict__ aw,
                          int E, int ET){
  int e = blockIdx.x*blockDim.x + threadIdx.x;
  if (e >= ET) return;
  int sN = e < E ? ei[e]   : e-E;
  int dN = e < E ? ei[E+e] : e-E;
  int pos = atomicAdd(&cur[dN], 1);
  srcs[pos] = sN;
  float4 ex = *(const float4*)&eo[(size_t)e*4];
  float4 sv = *(const float4*)&ssum[(size_t)dN*4];
  float4 a = make_float4(ex.x/(sv.x+1e-16f), ex.y/(sv.y+1e-16f),
                         ex.z/(sv.z+1e-16f), ex.w/(sv.w+1e-16f));
  *(float4*)&aw[(size_t)pos*4] = a;
}

// ---- CSR aggregation (proven): agg[d,:] = sum_i alpha[i]*h2[srcs[i],:] ----
__global__ __launch_bounds__(256) void k_agg(const int* __restrict__ rowptr,
                                             const int* __restrict__ srcs,
                                             const float* __restrict__ aw,
                                             const unsigned* __restrict__ h2v,
                                             float* __restrict__ agg, int n){
  int d = blockIdx.x, tid = threadIdx.x, head = tid>>6;
  int beg = rowptr[d], end = rowptr[d+1];
  float ax = 0.f, ay = 0.f;
  #pragma unroll 4
  for (int i=beg; i<end; ++i){
    int s   = srcs[i];
    float a = aw[(size_t)i*4 + head];
    unsigned v = h2v[(size_t)s*256 + tid];
    float f0 = __uint_as_float(v << 16);
    float f1 = __uint_as_float(v & 0xffff0000u);
    ax = fmaf(f0, a, ax);
    ay = fmaf(f1, a, ay);
  }
  *(float2*)&agg[(size_t)d*HC + tid*2] = make_float2(ax, ay);
}

// ---- epilogue (layout-adaptive): y = LN(relu(agg+gb) @ proj_w + pb + x) ----
// block 256 (4 waves), tile 32 rows x 128 cols.
__global__ __launch_bounds__(256) void k_epi(const float* __restrict__ agg,
                                             const float* __restrict__ gb,
                                             const unsigned short* __restrict__ BT,
                                             const float* __restrict__ pb,
                                             const float* __restrict__ x,
                                             const float* __restrict__ lng,
                                             const float* __restrict__ lnb,
                                             const int* __restrict__ flagp,
                                             float* __restrict__ y, int n){
  __shared__ float os[32*132];
  int row0 = blockIdx.x*32;
  int tid = threadIdx.x;
  int fl = *flagp;

  if (fl >= 1 && fl <= 3){
    // MFMA path with corrected layout per probe
    int w = tid>>6, l = tid&63;
    int rbase = 16*(w>>1), cbase = 64*(w&1);
    int g = l>>4, cl = l&15;
    int arow = row0 + rbase + cl; if (arow >= n) arow = n-1;
    const float* ap = agg + (size_t)arow*HC;
    f32x4 acc[4];
    #pragma unroll
    for (int i=0;i<4;++i) acc[i] = (f32x4){0.f,0.f,0.f,0.f};
    for (int ks=0; ks<16; ++ks){
      BF8 A;
      if (fl == 3){
        int b0 = ks*32 + 4*g;
        float4 a0 = *(const float4*)&ap[b0];
        float4 a1 = *(const float4*)&ap[b0+16];
        float4 g0 = *(const float4*)&gb[b0];
        float4 g1 = *(const float4*)&gb[b0+16];
        #pragma unroll
        for (int j=0;j<4;++j){
          A.u[j]   = f2bf(fmaxf(((const float*)&a0)[j] + ((const float*)&g0)[j], 0.f));
          A.u[4+j] = f2bf(fmaxf(((const float*)&a1)[j] + ((const float*)&g1)[j], 0.f));
        }
      } else {
        int b0 = ks*32 + 8*g;
        float4 a0 = *(const float4*)&ap[b0];
        float4 a1 = *(const float4*)&ap[b0+4];
        float4 g0 = *(const float4*)&gb[b0];
        float4 g1 = *(const float4*)&gb[b0+4];
        #pragma unroll
        for (int j=0;j<4;++j){
          A.u[j]   = f2bf(fmaxf(((const float*)&a0)[j] + ((const float*)&g0)[j], 0.f));
          A.u[4+j] = f2bf(fmaxf(((const float*)&a1)[j] + ((const float*)&g1)[j], 0.f));
        }
      }
      #pragma unroll
      for (int ct=0; ct<4; ++ct){
        int col = cbase + ct*16 + cl;
        int cb = col*512 + ks*32;
        BF8 B;
        if (fl == 2){
          int o = cb + 4*g;
          uint2 lo = *(const uint2*)&BT[o];
          uint2 hi = *(const uint2*)&BT[o+16];
          B.u32[0]=lo.x; B.u32[1]=lo.y; B.u32[2]=hi.x; B.u32[3]=hi.y;
        } else {
          B.v = *(const bf16x8*)&BT[cb + 8*g];
        }
        acc[ct] = __builtin_amdgcn_mfma_f32_16x16x32_bf16(A.v, B.v, acc[ct], 0, 0, 0);
      }
    }
    if (fl == 1){
      #pragma unroll
      for (int ct=0; ct<4; ++ct)
        #pragma unroll
        for (int r=0;r<4;++r)
          os[(rbase + cl)*132 + cbase + ct*16 + g*4 + r] = acc[ct][r];
    } else {
      #pragma unroll
      for (int ct=0; ct<4; ++ct)
        #pragma unroll
        for (int r=0;r<4;++r)
          os[(rbase + g*4 + r)*132 + cbase + ct*16 + cl] = acc[ct][r];
    }
  } else {
    // VALU fallback (fl==0: MFMA "verified" but empirically untrusted; fl==4: unknown layout)
    int rt = tid>>3, cc0 = (tid&7)*16;
    int rg = row0 + rt; int rr = rg < n ? rg : n-1;
    const float* ap = agg + (size_t)rr*HC;
    float accv[16];
    #pragma unroll
    for (int j=0;j<16;++j) accv[j] = 0.f;
    for (int k=0;k<HC;++k){
      float a = bf2f(f2bf(fmaxf(ap[k] + gb[k], 0.f)));
      #pragma unroll
      for (int j=0;j<16;++j)
        accv[j] = fmaf(a, bf2f(BT[(size_t)(cc0+j)*HC + k]), accv[j]);
    }
    #pragma unroll
    for (int j=0;j<16;++j) os[rt*132 + cc0 + j] = accv[j];
  }
  __syncthreads();

  // LN: thread t -> row t>>3, cols (t&7)*16..+16
  int r = tid>>3, c0 = (tid&7)*16;
  int row_g = row0 + r;
  bool live = row_g < n;
  int rx = live ? row_g : n-1;
  float v[16]; float sum=0.f, sq=0.f;
  #pragma unroll
  for (int j=0;j<16;++j){
    int c = c0+j;
    float t = os[r*132 + c] + pb[c] + x[(size_t)rx*COUT + c];
    v[j]=t; sum+=t; sq = fmaf(t,t,sq);
  }
  #pragma unroll
  for (int off=1; off<8; off<<=1){ sum += __shfl_xor(sum, off); sq += __shfl_xor(sq, off); }
  float mean = sum*(1.f/128.f);
  float var  = sq*(1.f/128.f) - mean*mean;
  float rstd = rsqrtf(var + 1e-5f);
  if (live){
    float o[16];
    #pragma unroll
    for (int j=0;j<16;++j) o[j] = (v[j]-mean)*rstd*lng[c0+j] + lnb[c0+j];
    float* yp = y + (size_t)row_g*COUT + c0;
    *(float4*)yp      = make_float4(o[0],o[1],o[2],o[3]);
    *(float4*)(yp+4)  = make_float4(o[4],o[5],o[6],o[7]);
    *(float4*)(yp+8)  = make_float4(o[8],o[9],o[10],o[11]);
    *(float4*)(yp+12) = make_float4(o[12],o[13],o[14],o[15]);
  }
}

extern "C" void kernel_launch(void* const* d_in, const int* in_sizes, int n_in,
                              void* d_out, int out_size, void* d_ws, size_t ws_size,
                              hipStream_t stream){
  const float* x        = (const float*)d_in[0];
  const int*   ei       = (const int*)  d_in[1];
  const float* lin_w    = (const float*)d_in[2];
  const float* att_src  = (const float*)d_in[3];
  const float* att_dst  = (const float*)d_in[4];
  const float* gat_bias = (const float*)d_in[5];
  const float* proj_w   = (const float*)d_in[6];
  const float* proj_b   = (const float*)d_in[7];
  const float* ln_g     = (const float*)d_in[8];
  const float* ln_b     = (const float*)d_in[9];
  float* y = (float*)d_out;

  int n  = in_sizes[0]/CIN;
  int E  = in_sizes[1]/2;
  int ET = E + n;

  char* p = (char*)d_ws;
  auto alloc = [&](size_t bytes)->char*{
    char* r = p; p += (bytes + 255) & ~(size_t)255; return r;
  };
  unsigned short* h2 = (unsigned short*)alloc((size_t)n*HC*2);
  float*    agg    = (float*)   alloc((size_t)n*HC*4);
  unsigned short* BT = (unsigned short*)alloc((size_t)65536*2);
  int*      flag   = (int*)     alloc(256);
  float*    asrc   = (float*)   alloc((size_t)n*4*4);
  float*    adst   = (float*)   alloc((size_t)n*4*4);
  unsigned* m      = (unsigned*)alloc((size_t)n*4*4);
  float*    ssum   = (float*)   alloc((size_t)n*4*4);
  float*    eo     = (float*)   alloc((size_t)ET*4*4);
  int*      hist   = (int*)     alloc((size_t)n*4);
  int*      scn    = (int*)     alloc((size_t)n*4);
  int*      rowptr = (int*)     alloc((size_t)(n+1)*4);
  int*      cursor = (int*)     alloc((size_t)n*4);
  int*      srcs   = (int*)     alloc((size_t)ET*4);
  float*    aw     = (float*)   alloc((size_t)ET*4*4);
  int T = (n + STILE-1)/STILE;
  int*      tsum   = (int*)     alloc((size_t)T*4);

  k_probe  <<<1, 64, 0, stream>>>(flag);
  k_init   <<<(4*n+255)/256, 256, 0, stream>>>(m, ssum, hist, n);
  k_prep   <<<256, 256, 0, stream>>>(proj_w, BT);
  k_lin    <<<(n+7)/8, 64, 0, stream>>>(x, lin_w, att_src, att_dst, h2, asrc, adst, n);
  k_logits <<<(ET+255)/256, 256, 0, stream>>>(ei, asrc, adst, eo, m, hist, E, ET);
  k_scan1  <<<T, 1024, 0, stream>>>(hist, scn, tsum, n);
  k_scan2  <<<1, 64, 0, stream>>>(tsum, T);
  k_scan3  <<<(n+255)/256, 256, 0, stream>>>(scn, tsum, rowptr, cursor, n);
  k_expsum <<<(ET+255)/256, 256, 0, stream>>>(ei, eo, m, ssum, E, ET);
  k_scatter<<<(ET+255)/256, 256, 0, stream>>>(ei, cursor, eo, ssum, srcs, aw, E, ET);
  k_agg    <<<n, 256, 0, stream>>>(rowptr, srcs, aw, (const unsigned*)h2, agg, n);
  k_epi    <<<(n+31)/32, 256, 0, stream>>>(agg, gat_bias, BT, proj_b, x, ln_g, ln_b, flag, y, n);
}

// Round 9
// 1993.903 us; speedup vs baseline: 1.8878x; 1.8878x over previous
//
#include <hip/hip_runtime.h>
#include <math.h>

#define HEADS 4
#define HC 512          // HEADS * OUT_CH
#define CIN 128
#define COUT 128
#define NEG_SLOPE 0.2f

typedef __attribute__((ext_vector_type(8))) short bf16x8;
typedef __attribute__((ext_vector_type(4))) float f32x4;

union BF8 { unsigned short u[8]; unsigned u32[4]; bf16x8 v; };

// ---- float <-> ordered-uint encoding for atomic max on floats ----
__device__ __forceinline__ unsigned enc_f(float f){
  unsigned u = __float_as_uint(f);
  return (u & 0x80000000u) ? ~u : (u | 0x80000000u);
}
__device__ __forceinline__ float dec_f(unsigned k){
  unsigned u = (k & 0x80000000u) ? (k & 0x7fffffffu) : ~k;
  return __uint_as_float(u);
}
#define ENC_NEGINF 0x007FFFFFu   // enc(-inf)

__device__ __forceinline__ unsigned short f2bf(float f){
  unsigned u = __float_as_uint(f);
  unsigned r = u + 0x7fffu + ((u >> 16) & 1u);   // RNE
  return (unsigned short)(r >> 16);
}
__device__ __forceinline__ float bf2f(unsigned short s){
  return __uint_as_float((unsigned)s << 16);
}

// ================= MFMA layout diagnostic =================
// Writes tbl[70] = V, bits:
//  1: b0 e0-recipe exact (A,B contiguous-8, C row=4g+j col=lane&15)
//  2: b1 C-transposed variant exact
//  4: b2 learned-table end-to-end exact (r8 recipe)
//  8: b3 slot-pairing rho == identity
// 16: b4 measured C labels == guide (rlab=4g+j, clab=lane&15)
__global__ void k_probe(int* __restrict__ tbl){
  int l = threadIdx.x;
  int g = l>>4, c = l&15;
  BF8 A, B; f32x4 acc;
  bool b0=true,b1=true,b2=true,b3=true,b4=true;

  // ---- b0/b1: asymmetric integer matrices, contiguous-8 loading ----
  #pragma unroll
  for (int i=0;i<8;++i){
    int m=8*g+i;
    A.u[i]=f2bf((float)((c*5+m*3)&7));
    B.u[i]=f2bf((float)((c*3+m*5)&7));
  }
  acc=(f32x4){0.f,0.f,0.f,0.f};
  acc=__builtin_amdgcn_mfma_f32_16x16x32_bf16(A.v,B.v,acc,0,0,0);
  #pragma unroll
  for (int j=0;j<4;++j){
    int r0=4*g+j;
    int ex0=0, ex1=0;
    for (int m=0;m<32;++m){
      ex0 += ((r0*5+m*3)&7)*((c*3+m*5)&7);
      ex1 += ((c*5+m*3)&7)*((r0*3+m*5)&7);
    }
    b0 = b0 && (acc[j]==(float)ex0);
    b1 = b1 && (acc[j]==(float)ex1);
  }

  // ---- measured C labels ----
  #pragma unroll
  for (int i=0;i<8;++i){ A.u[i]=f2bf(1.f); B.u[i]=f2bf((float)c); }
  acc=(f32x4){0.f,0.f,0.f,0.f};
  acc=__builtin_amdgcn_mfma_f32_16x16x32_bf16(A.v,B.v,acc,0,0,0);
  int clab[4];
  #pragma unroll
  for (int j=0;j<4;++j){
    clab[j]=(int)(acc[j]*(1.f/32.f)+0.5f);
    b2 = b2 && (acc[j]==32.f*(float)clab[j]) && clab[j]>=0 && clab[j]<16;
  }
  #pragma unroll
  for (int i=0;i<8;++i){ A.u[i]=f2bf((float)c); B.u[i]=f2bf(1.f); }
  acc=(f32x4){0.f,0.f,0.f,0.f};
  acc=__builtin_amdgcn_mfma_f32_16x16x32_bf16(A.v,B.v,acc,0,0,0);
  int rlab[4];
  #pragma unroll
  for (int j=0;j<4;++j){
    rlab[j]=(int)(acc[j]*(1.f/32.f)+0.5f);
    b2 = b2 && (acc[j]==32.f*(float)rlab[j]) && rlab[j]>=0 && rlab[j]<16;
  }
  #pragma unroll
  for (int j=0;j<4;++j) b4 = b4 && (rlab[j]==4*g+j) && (clab[j]==c);

  // ---- pairing rho ----
  int rho[32];
  #pragma unroll
  for (int i=0;i<8;++i) B.u[i]=f2bf((float)(8*g+i));
  for (int m0=0;m0<32;++m0){
    #pragma unroll
    for (int i=0;i<8;++i) A.u[i]=f2bf((8*g+i)==m0 ? 1.f : 0.f);
    acc=(f32x4){0.f,0.f,0.f,0.f};
    acc=__builtin_amdgcn_mfma_f32_16x16x32_bf16(A.v,B.v,acc,0,0,0);
    float v=acc[0];
    b2 = b2 && (acc[1]==v) && (acc[2]==v) && (acc[3]==v);
    float v0=__shfl(v,0);
    b2 = b2 && (v==v0);
    int r_=(int)(v0+0.5f);
    b2 = b2 && (v0==(float)r_) && r_>=0 && r_<32;
    rho[m0]=r_&31;
  }
  unsigned msk=0;
  for (int m=0;m<32;++m) msk |= (1u<<rho[m]);
  b2 = b2 && (msk==0xffffffffu);
  int rinv[32];
  for (int m=0;m<32;++m) rinv[rho[m]&31]=m;
  b3 = true;
  for (int m=0;m<32;++m) b3 = b3 && (rho[m]==m);

  // ---- b2: learned-table end-to-end ----
  #pragma unroll
  for (int i=0;i<8;++i){
    int m=8*g+i;
    A.u[i]=f2bf((float)((c*5+m*3)&7));
    int mm=rinv[m];
    B.u[i]=f2bf((float)((c*3+mm*5)&7));
  }
  acc=(f32x4){0.f,0.f,0.f,0.f};
  acc=__builtin_amdgcn_mfma_f32_16x16x32_bf16(A.v,B.v,acc,0,0,0);
  #pragma unroll
  for (int j=0;j<4;++j){
    int r=rlab[j]&15, cc=clab[j]&15;
    int ex=0;
    for (int m=0;m<32;++m) ex += ((r*5+m*3)&7)*((cc*3+m*5)&7);
    b2 = b2 && (acc[j]==(float)ex);
  }

  int v = (__all(b0?1:0)?1:0) | (__all(b1?1:0)?2:0) | (__all(b2?1:0)?4:0)
        | (__all(b3?1:0)?8:0) | (__all(b4?1:0)?16:0);
  if (l==0) tbl[70]=v;
}

// spin kernel: only the instance matching tbl[70] burns ~800us -> its NAME
// in the rocprof top-5 encodes the probe verdict.
template<int I>
__global__ void k_v(int* __restrict__ tbl){
  if (tbl[70] != I) return;
  float xx = 1.0f + (float)threadIdx.x;
  for (int it=0; it<480000; ++it) xx = fmaf(xx, 1.0000001f, 1.0f);
  tbl[128 + threadIdx.x] = __float_as_int(xx);
}

// ================= proven 827us carrier pipeline =================

__global__ void k_init(unsigned* __restrict__ m, float* __restrict__ s,
                       int* __restrict__ hist, int n){
  int i = blockIdx.x*blockDim.x + threadIdx.x;
  if (i < 4*n){ m[i] = ENC_NEGINF; s[i] = 0.f; }
  if (i < n) hist[i] = 0;
}

// GEMM1 fused: h2 = bf16(x @ lin_w); asrc/adst dots (fp32 VALU, proven)
__global__ __launch_bounds__(64) void k_lin(const float* __restrict__ x,
                                            const float* __restrict__ w,
                                            const float* __restrict__ as_w,
                                            const float* __restrict__ ad_w,
                                            unsigned short* __restrict__ h2,
                                            float* __restrict__ asrc,
                                            float* __restrict__ adst, int n){
  __shared__ float xs[8*CIN];
  int row0 = blockIdx.x*8;
  int tid  = threadIdx.x;
  int rows = n - row0; if (rows > 8) rows = 8;
  const float4* x4 = (const float4*)(x + (size_t)row0*CIN);
  float4* xs4 = (float4*)xs;
  #pragma unroll
  for (int i=0;i<4;++i){
    int f = i*64 + tid;
    float4 v = (f>>5) < rows ? x4[f] : make_float4(0,0,0,0);
    xs4[f] = v;
  }
  __syncthreads();
  float acc[8][8];
  #pragma unroll
  for (int r=0;r<8;++r)
    #pragma unroll
    for (int c=0;c<8;++c) acc[r][c] = 0.f;
  int c0 = tid*8;
  for (int k=0;k<CIN;k+=4){
    float4 xv[8];
    #pragma unroll
    for (int r=0;r<8;++r) xv[r] = *(const float4*)&xs[r*CIN+k];
    #pragma unroll
    for (int kk=0;kk<4;++kk){
      float4 w0 = *(const float4*)&w[(size_t)(k+kk)*HC + c0];
      float4 w1 = *(const float4*)&w[(size_t)(k+kk)*HC + c0 + 4];
      float wv[8] = {w0.x,w0.y,w0.z,w0.w,w1.x,w1.y,w1.z,w1.w};
      #pragma unroll
      for (int r=0;r<8;++r){
        float a = ((const float*)&xv[r])[kk];
        #pragma unroll
        for (int c=0;c<8;++c) acc[r][c] = fmaf(a, wv[c], acc[r][c]);
      }
    }
  }
  int head = tid >> 4;
  int cc   = (tid & 15) * 8;
  float asv[8], adv[8];
  #pragma unroll
  for (int c=0;c<8;++c){ asv[c] = as_w[head*COUT + cc + c]; adv[c] = ad_w[head*COUT + cc + c]; }
  #pragma unroll
  for (int r=0;r<8;++r){
    if (r >= rows) break;
    unsigned short vs[8];
    #pragma unroll
    for (int c=0;c<8;++c) vs[c] = f2bf(acc[r][c]);
    *(uint4*)&h2[(size_t)(row0+r)*HC + c0] = *(uint4*)vs;
    float ps = 0.f, pd = 0.f;
    #pragma unroll
    for (int c=0;c<8;++c){ ps = fmaf(acc[r][c], asv[c], ps); pd = fmaf(acc[r][c], adv[c], pd); }
    #pragma unroll
    for (int off=1; off<16; off<<=1){ ps += __shfl_xor(ps, off); pd += __shfl_xor(pd, off); }
    if ((tid & 15) == 0){
      asrc[(size_t)(row0+r)*4 + head] = ps;
      adst[(size_t)(row0+r)*4 + head] = pd;
    }
  }
}

__global__ void k_logits(const int* __restrict__ ei, const float* __restrict__ asrc,
                         const float* __restrict__ adst, float* __restrict__ eo,
                         unsigned* __restrict__ m, int* __restrict__ hist,
                         int E, int ET){
  int e = blockIdx.x*blockDim.x + threadIdx.x;
  if (e >= ET) return;
  int sN = e < E ? ei[e]   : e-E;
  int dN = e < E ? ei[E+e] : e-E;
  atomicAdd(&hist[dN], 1);
  #pragma unroll
  for (int hh=0; hh<4; ++hh){
    float lg = asrc[sN*4+hh] + adst[dN*4+hh];
    lg = lg > 0.f ? lg : NEG_SLOPE*lg;
    eo[(size_t)e*4+hh] = lg;
    atomicMax(&m[dN*4+hh], enc_f(lg));
  }
}

#define STILE 4096
__global__ __launch_bounds__(1024) void k_scan1(const int* __restrict__ in,
                                                int* __restrict__ out,
                                                int* __restrict__ tsum, int n){
  __shared__ int ls[1024];
  int b = blockIdx.x, tid = threadIdx.x;
  int base = b*STILE + tid*4;
  int v[4];
  #pragma unroll
  for (int i=0;i<4;++i){ int idx=base+i; v[i] = idx<n ? in[idx] : 0; }
  int run = v[0]+v[1]+v[2]+v[3];
  ls[tid]=run; __syncthreads();
  for (int off=1; off<1024; off<<=1){
    int t = (tid>=off) ? ls[tid-off] : 0;
    __syncthreads();
    ls[tid]+=t; __syncthreads();
  }
  int excl = ls[tid]-run;
  int sv[4]; sv[0]=excl+v[0]; sv[1]=sv[0]+v[1]; sv[2]=sv[1]+v[2]; sv[3]=sv[2]+v[3];
  #pragma unroll
  for (int i=0;i<4;++i){ int idx=base+i; if (idx<n) out[idx]=sv[i]; }
  if (tid==1023) tsum[b]=ls[1023];
}
__global__ void k_scan2(int* __restrict__ tsum, int T){
  if (threadIdx.x==0 && blockIdx.x==0){
    int off=0;
    for (int t=0;t<T;++t){ int v=tsum[t]; tsum[t]=off; off+=v; }
  }
}
__global__ void k_scan3(const int* __restrict__ scn, const int* __restrict__ toff,
                        int* __restrict__ rowptr, int* __restrict__ cur, int n){
  int i = blockIdx.x*blockDim.x + threadIdx.x;
  if (i<n){
    rowptr[i+1] = scn[i] + toff[i/STILE];
    cur[i] = (i==0) ? 0 : scn[i-1] + toff[(i-1)/STILE];
  }
  if (i==0) rowptr[0] = 0;
}

__global__ void k_expsum(const int* __restrict__ ei, float* __restrict__ eo,
                         const unsigned* __restrict__ m, float* __restrict__ s,
                         int E, int ET){
  int e = blockIdx.x*blockDim.x + threadIdx.x;
  if (e >= ET) return;
  int dN = e < E ? ei[E+e] : e-E;
  #pragma unroll
  for (int hh=0; hh<4; ++hh){
    float ex = expf(eo[(size_t)e*4+hh] - dec_f(m[dN*4+hh]));
    eo[(size_t)e*4+hh] = ex;
    atomicAdd(&s[dN*4+hh], ex);
  }
}

__global__ void k_scatter(const int* __restrict__ ei, int* __restrict__ cur,
                          const float* __restrict__ eo, const float* __restrict__ ssum,
                          int* __restrict__ srcs, float* __restrict__ aw,
                          int E, int ET){
  int e = blockIdx.x*blockDim.x + threadIdx.x;
  if (e >= ET) return;
  int sN = e < E ? ei[e]   : e-E;
  int dN = e < E ? ei[E+e] : e-E;
  int pos = atomicAdd(&cur[dN], 1);
  srcs[pos] = sN;
  float4 ex = *(const float4*)&eo[(size_t)e*4];
  float4 sv = *(const float4*)&ssum[(size_t)dN*4];
  float4 a = make_float4(ex.x/(sv.x+1e-16f), ex.y/(sv.y+1e-16f),
                         ex.z/(sv.z+1e-16f), ex.w/(sv.w+1e-16f));
  *(float4*)&aw[(size_t)pos*4] = a;
}

__global__ __launch_bounds__(256) void k_agg(const int* __restrict__ rowptr,
                                             const int* __restrict__ srcs,
                                             const float* __restrict__ aw,
                                             const unsigned* __restrict__ h2v,
                                             float* __restrict__ agg, int n){
  int d = blockIdx.x, tid = threadIdx.x, head = tid>>6;
  int beg = rowptr[d], end = rowptr[d+1];
  float ax = 0.f, ay = 0.f;
  #pragma unroll 4
  for (int i=beg; i<end; ++i){
    int s   = srcs[i];
    float a = aw[(size_t)i*4 + head];
    unsigned v = h2v[(size_t)s*256 + tid];
    float f0 = __uint_as_float(v << 16);
    float f1 = __uint_as_float(v & 0xffff0000u);
    ax = fmaf(f0, a, ax);
    ay = fmaf(f1, a, ay);
  }
  *(float2*)&agg[(size_t)d*HC + tid*2] = make_float2(ax, ay);
}

#define EPAD 516
__global__ __launch_bounds__(64) void k_epi(const float* __restrict__ agg,
                                            const float* __restrict__ gb,
                                            const float* __restrict__ pw,
                                            const float* __restrict__ pb,
                                            const float* __restrict__ x,
                                            const float* __restrict__ lng,
                                            const float* __restrict__ lnb,
                                            float* __restrict__ y, int n){
  __shared__ float sr[8*EPAD];
  int row0 = blockIdx.x*8, tid = threadIdx.x;
  int rows = n - row0; if (rows > 8) rows = 8;
  const float4* a4  = (const float4*)(agg + (size_t)row0*HC);
  const float4* gb4 = (const float4*)gb;
  #pragma unroll
  for (int i=0;i<16;++i){
    int f = i*64 + tid;
    int r = f>>7, kq = f & 127;
    float4 v = (r < rows) ? a4[f] : make_float4(0,0,0,0);
    float4 g = gb4[kq];
    v.x = fmaxf(v.x+g.x, 0.f); v.y = fmaxf(v.y+g.y, 0.f);
    v.z = fmaxf(v.z+g.z, 0.f); v.w = fmaxf(v.w+g.w, 0.f);
    *(float4*)&sr[r*EPAD + kq*4] = v;
  }
  __syncthreads();
  int tr = tid>>4, tc = tid&15;
  int r0 = tr*2, c0 = tc*8;
  float acc[2][8];
  #pragma unroll
  for (int rr=0;rr<2;++rr)
    #pragma unroll
    for (int c=0;c<8;++c) acc[rr][c]=0.f;
  for (int k=0;k<HC;k+=4){
    float4 a0 = *(const float4*)&sr[r0*EPAD + k];
    float4 a1 = *(const float4*)&sr[(r0+1)*EPAD + k];
    #pragma unroll
    for (int kk=0;kk<4;++kk){
      float4 w0 = *(const float4*)&pw[(size_t)(k+kk)*COUT + c0];
      float4 w1 = *(const float4*)&pw[(size_t)(k+kk)*COUT + c0 + 4];
      float wv[8] = {w0.x,w0.y,w0.z,w0.w,w1.x,w1.y,w1.z,w1.w};
      float av0 = ((const float*)&a0)[kk];
      float av1 = ((const float*)&a1)[kk];
      #pragma unroll
      for (int c=0;c<8;++c){
        acc[0][c] = fmaf(av0, wv[c], acc[0][c]);
        acc[1][c] = fmaf(av1, wv[c], acc[1][c]);
      }
    }
  }
  #pragma unroll
  for (int rr=0;rr<2;++rr){
    int row = row0 + r0 + rr;
    bool live = (r0+rr) < rows;
    float v[8]; float sum=0.f, sq=0.f;
    #pragma unroll
    for (int c=0;c<8;++c){
      float xv = live ? x[(size_t)row*COUT + c0 + c] : 0.f;
      float t = acc[rr][c] + pb[c0+c] + xv;
      v[c]=t; sum+=t; sq = fmaf(t,t,sq);
    }
    #pragma unroll
    for (int off=1; off<16; off<<=1){ sum += __shfl_xor(sum, off); sq += __shfl_xor(sq, off); }
    float mean = sum*(1.f/128.f);
    float var  = sq*(1.f/128.f) - mean*mean;
    float rstd = rsqrtf(var + 1e-5f);
    if (live){
      float o[8];
      #pragma unroll
      for (int c=0;c<8;++c) o[c] = (v[c]-mean)*rstd*lng[c0+c] + lnb[c0+c];
      float* yp = y + (size_t)row*COUT + c0;
      *(float4*)yp     = make_float4(o[0],o[1],o[2],o[3]);
      *(float4*)(yp+4) = make_float4(o[4],o[5],o[6],o[7]);
    }
  }
}

extern "C" void kernel_launch(void* const* d_in, const int* in_sizes, int n_in,
                              void* d_out, int out_size, void* d_ws, size_t ws_size,
                              hipStream_t stream){
  const float* x        = (const float*)d_in[0];
  const int*   ei       = (const int*)  d_in[1];
  const float* lin_w    = (const float*)d_in[2];
  const float* att_src  = (const float*)d_in[3];
  const float* att_dst  = (const float*)d_in[4];
  const float* gat_bias = (const float*)d_in[5];
  const float* proj_w   = (const float*)d_in[6];
  const float* proj_b   = (const float*)d_in[7];
  const float* ln_g     = (const float*)d_in[8];
  const float* ln_b     = (const float*)d_in[9];
  float* y = (float*)d_out;

  int n  = in_sizes[0]/CIN;
  int E  = in_sizes[1]/2;
  int ET = E + n;

  char* p = (char*)d_ws;
  auto alloc = [&](size_t bytes)->char*{
    char* r = p; p += (bytes + 255) & ~(size_t)255; return r;
  };
  unsigned short* h2 = (unsigned short*)alloc((size_t)n*HC*2);
  float*    agg    = (float*)   alloc((size_t)n*HC*4);
  int*      tbl    = (int*)     alloc(4096);
  float*    asrc   = (float*)   alloc((size_t)n*4*4);
  float*    adst   = (float*)   alloc((size_t)n*4*4);
  unsigned* m      = (unsigned*)alloc((size_t)n*4*4);
  float*    ssum   = (float*)   alloc((size_t)n*4*4);
  float*    eo     = (float*)   alloc((size_t)ET*4*4);
  int*      hist   = (int*)     alloc((size_t)n*4);
  int*      scn    = (int*)     alloc((size_t)n*4);
  int*      rowptr = (int*)     alloc((size_t)(n+1)*4);
  int*      cursor = (int*)     alloc((size_t)n*4);
  int*      srcs   = (int*)     alloc((size_t)ET*4);
  float*    aw     = (float*)   alloc((size_t)ET*4*4);
  int T = (n + STILE-1)/STILE;
  int*      tsum   = (int*)     alloc((size_t)T*4);

  k_probe  <<<1, 64, 0, stream>>>(tbl);
  k_init   <<<(4*n+255)/256, 256, 0, stream>>>(m, ssum, hist, n);
  k_lin    <<<(n+7)/8, 64, 0, stream>>>(x, lin_w, att_src, att_dst, h2, asrc, adst, n);
  k_logits <<<(ET+255)/256, 256, 0, stream>>>(ei, asrc, adst, eo, m, hist, E, ET);
  k_scan1  <<<T, 1024, 0, stream>>>(hist, scn, tsum, n);
  k_scan2  <<<1, 64, 0, stream>>>(tsum, T);
  k_scan3  <<<(n+255)/256, 256, 0, stream>>>(scn, tsum, rowptr, cursor, n);
  k_expsum <<<(ET+255)/256, 256, 0, stream>>>(ei, eo, m, ssum, E, ET);
  k_scatter<<<(ET+255)/256, 256, 0, stream>>>(ei, cursor, eo, ssum, srcs, aw, E, ET);
  k_agg    <<<n, 256, 0, stream>>>(rowptr, srcs, aw, (const unsigned*)h2, agg, n);
  k_epi    <<<(n+7)/8, 64, 0, stream>>>(agg, gat_bias, proj_w, proj_b, x, ln_g, ln_b, y, n);

  // diagnostic spin: only k_v<tbl[70]> burns time; its name in the profile
  // is the probe verdict.
#define LV(I) k_v<I><<<1, 64, 0, stream>>>(tbl)
  LV(0); LV(1); LV(2); LV(3); LV(4); LV(5); LV(6); LV(7);
  LV(8); LV(9); LV(10); LV(11); LV(12); LV(13); LV(14); LV(15);
  LV(16); LV(17); LV(18); LV(19); LV(20); LV(21); LV(22); LV(23);
  LV(24); LV(25); LV(26); LV(27); LV(28); LV(29); LV(30); LV(31);
#undef LV
}

// Round 10
// 1222.865 us; speedup vs baseline: 3.0780x; 1.6305x over previous
//
#include <hip/hip_runtime.h>
#include <math.h>

#define HEADS 4
#define HC 512          // HEADS * OUT_CH
#define CIN 128
#define COUT 128
#define NEG_SLOPE 0.2f

typedef __attribute__((ext_vector_type(8))) short bf16x8;
typedef __attribute__((ext_vector_type(4))) float f32x4;

union BF8 { unsigned short u[8]; unsigned u32[4]; bf16x8 v; };

__device__ __forceinline__ unsigned enc_f(float f){
  unsigned u = __float_as_uint(f);
  return (u & 0x80000000u) ? ~u : (u | 0x80000000u);
}
__device__ __forceinline__ float dec_f(unsigned k){
  unsigned u = (k & 0x80000000u) ? (k & 0x7fffffffu) : ~k;
  return __uint_as_float(u);
}
#define ENC_NEGINF 0x007FFFFFu

__device__ __forceinline__ unsigned short f2bf(float f){
  unsigned u = __float_as_uint(f);
  unsigned r = u + 0x7fffu + ((u >> 16) & 1u);   // RNE
  return (unsigned short)(r >> 16);
}
__device__ __forceinline__ float bf2f(unsigned short s){
  return __uint_as_float((unsigned)s << 16);
}

__device__ __forceinline__ int exref0(int r, int c){
  int ex=0;
  for (int m=0;m<32;++m) ex += ((r*5+m*3)&7)*((c*3+m*5)&7);
  return ex;
}
__device__ __forceinline__ int exref1(int r, int c){
  int ex=0;
  for (int m=0;m<32;++m) ex += ((c*5+m*3)&7)*((r*3+m*5)&7);
  return ex;
}

// ---- MFMA layout diagnostic. tbl[70] = 5-bit verdict V. ----
// bit0: e0 recipe exact (union-built contiguous-8 A/B, C: row=4g+j col=lane&15)
// bit1: C-transposed variant exact
// bit2: learned-table (labels+rho) self-consistency verified
// bit3: e0 exact with EPI-STYLE construction (global fp32->float4->f2bf->cast A;
//       global bf16x8 load B)  -- isolates construction/compiler effects
// bit4: measured C labels == guide mapping
__global__ void k_probe(int* __restrict__ tbl){
  int l = threadIdx.x;
  int g = l>>4, c = l&15;
  BF8 A, B; f32x4 acc;
  bool b0=true,b1=true,b2=true,b3=true,b4=true;

  // bit0/bit1
  #pragma unroll
  for (int i=0;i<8;++i){
    int m=8*g+i;
    A.u[i]=f2bf((float)((c*5+m*3)&7));
    B.u[i]=f2bf((float)((c*3+m*5)&7));
  }
  acc=(f32x4){0.f,0.f,0.f,0.f};
  acc=__builtin_amdgcn_mfma_f32_16x16x32_bf16(A.v,B.v,acc,0,0,0);
  #pragma unroll
  for (int j=0;j<4;++j){
    int r0=4*g+j;
    b0 = b0 && (acc[j]==(float)exref0(r0,c));
    b1 = b1 && (acc[j]==(float)exref1(r0,c));
  }

  // C labels
  #pragma unroll
  for (int i=0;i<8;++i){ A.u[i]=f2bf(1.f); B.u[i]=f2bf((float)c); }
  acc=(f32x4){0.f,0.f,0.f,0.f};
  acc=__builtin_amdgcn_mfma_f32_16x16x32_bf16(A.v,B.v,acc,0,0,0);
  int clab[4];
  #pragma unroll
  for (int j=0;j<4;++j){
    clab[j]=(int)(acc[j]*(1.f/32.f)+0.5f);
    b2 = b2 && (acc[j]==32.f*(float)clab[j]) && clab[j]>=0 && clab[j]<16;
  }
  #pragma unroll
  for (int i=0;i<8;++i){ A.u[i]=f2bf((float)c); B.u[i]=f2bf(1.f); }
  acc=(f32x4){0.f,0.f,0.f,0.f};
  acc=__builtin_amdgcn_mfma_f32_16x16x32_bf16(A.v,B.v,acc,0,0,0);
  int rlab[4];
  #pragma unroll
  for (int j=0;j<4;++j){
    rlab[j]=(int)(acc[j]*(1.f/32.f)+0.5f);
    b2 = b2 && (acc[j]==32.f*(float)rlab[j]) && rlab[j]>=0 && rlab[j]<16;
  }
  #pragma unroll
  for (int j=0;j<4;++j) b4 = b4 && (rlab[j]==4*g+j) && (clab[j]==c);

  // pairing rho
  int rho[32];
  #pragma unroll
  for (int i=0;i<8;++i) B.u[i]=f2bf((float)(8*g+i));
  for (int m0=0;m0<32;++m0){
    #pragma unroll
    for (int i=0;i<8;++i) A.u[i]=f2bf((8*g+i)==m0 ? 1.f : 0.f);
    acc=(f32x4){0.f,0.f,0.f,0.f};
    acc=__builtin_amdgcn_mfma_f32_16x16x32_bf16(A.v,B.v,acc,0,0,0);
    float v=acc[0];
    b2 = b2 && (acc[1]==v) && (acc[2]==v) && (acc[3]==v);
    float v0=__shfl(v,0);
    b2 = b2 && (v==v0);
    int r_=(int)(v0+0.5f);
    b2 = b2 && (v0==(float)r_) && r_>=0 && r_<32;
    rho[m0]=r_&31;
  }
  unsigned msk=0;
  for (int m=0;m<32;++m) msk |= (1u<<rho[m]);
  b2 = b2 && (msk==0xffffffffu);
  int rinv[32];
  for (int m=0;m<32;++m) rinv[rho[m]&31]=m;

  // bit2 end-to-end with learned tables
  #pragma unroll
  for (int i=0;i<8;++i){
    int m=8*g+i;
    A.u[i]=f2bf((float)((c*5+m*3)&7));
    int mm=rinv[m];
    B.u[i]=f2bf((float)((c*3+mm*5)&7));
  }
  acc=(f32x4){0.f,0.f,0.f,0.f};
  acc=__builtin_amdgcn_mfma_f32_16x16x32_bf16(A.v,B.v,acc,0,0,0);
  #pragma unroll
  for (int j=0;j<4;++j)
    b2 = b2 && (acc[j]==(float)exref0(rlab[j]&15, clab[j]&15));

  // bit3: epi-style construction through global memory
  float* aF = (float*)&tbl[1024];              // 512 floats
  unsigned short* bS = (unsigned short*)&tbl[2048]; // 512 shorts
  #pragma unroll
  for (int i=0;i<8;++i){
    int m=8*g+i;
    aF[l*8+i] = (float)((c*5+m*3)&7);
    bS[l*8+i] = f2bf((float)((c*3+m*5)&7));
  }
  __threadfence();
  __syncthreads();
  float4 a0 = *(const float4*)&aF[l*8];
  float4 a1 = *(const float4*)&aF[l*8+4];
  float av[8] = {a0.x,a0.y,a0.z,a0.w,a1.x,a1.y,a1.z,a1.w};
  unsigned short af[8];
  #pragma unroll
  for (int j=0;j<8;++j) af[j] = f2bf(fmaxf(av[j], 0.f));
  bf16x8 a3 = *(bf16x8*)af;
  bf16x8 bb = *(const bf16x8*)&bS[l*8];
  acc=(f32x4){0.f,0.f,0.f,0.f};
  acc=__builtin_amdgcn_mfma_f32_16x16x32_bf16(a3,bb,acc,0,0,0);
  #pragma unroll
  for (int j=0;j<4;++j)
    b3 = b3 && (acc[j]==(float)exref0(4*g+j, c));

  int v = (__all(b0?1:0)?1:0) | (__all(b1?1:0)?2:0) | (__all(b2?1:0)?4:0)
        | (__all(b3?1:0)?8:0) | (__all(b4?1:0)?16:0);
  if (l<32){ tbl[l]=rho[l]; tbl[32+l]=rinv[l]; }
  #pragma unroll
  for (int j=0;j<4;++j){ tbl[80+l*8+j]=rlab[j]&15; tbl[80+l*8+4+j]=clab[j]&15; }
  if (l==0) tbl[70]=v;
}

// 32 distinctly-NAMED spin kernels: only k_verdict_<tbl[70]> burns ~500us.
#define DEFV(I) __global__ void k_verdict_##I(int* __restrict__ t){ \
  if (t[70] != I) return; \
  float xx = 1.0f + (float)threadIdx.x; \
  for (int it=0; it<200000; ++it) xx = fmaf(xx, 1.0000001f, 1.0f); \
  t[300 + threadIdx.x] = __float_as_int(xx); }
DEFV(0) DEFV(1) DEFV(2) DEFV(3) DEFV(4) DEFV(5) DEFV(6) DEFV(7)
DEFV(8) DEFV(9) DEFV(10) DEFV(11) DEFV(12) DEFV(13) DEFV(14) DEFV(15)
DEFV(16) DEFV(17) DEFV(18) DEFV(19) DEFV(20) DEFV(21) DEFV(22) DEFV(23)
DEFV(24) DEFV(25) DEFV(26) DEFV(27) DEFV(28) DEFV(29) DEFV(30) DEFV(31)

// ================= pipeline =================

__global__ void k_init(unsigned* __restrict__ m, float* __restrict__ s,
                       int* __restrict__ hist, int n){
  int i = blockIdx.x*blockDim.x + threadIdx.x;
  if (i < 4*n){ m[i] = ENC_NEGINF; s[i] = 0.f; }
  if (i < n) hist[i] = 0;
}

// GEMM1 (fp32 VALU, proven): h2 = bf16(x @ lin_w); fused asrc/adst
__global__ __launch_bounds__(64) void k_lin(const float* __restrict__ x,
                                            const float* __restrict__ w,
                                            const float* __restrict__ as_w,
                                            const float* __restrict__ ad_w,
                                            unsigned short* __restrict__ h2,
                                            float* __restrict__ asrc,
                                            float* __restrict__ adst, int n){
  __shared__ float xs[8*CIN];
  int row0 = blockIdx.x*8;
  int tid  = threadIdx.x;
  int rows = n - row0; if (rows > 8) rows = 8;
  const float4* x4 = (const float4*)(x + (size_t)row0*CIN);
  float4* xs4 = (float4*)xs;
  #pragma unroll
  for (int i=0;i<4;++i){
    int f = i*64 + tid;
    float4 v = (f>>5) < rows ? x4[f] : make_float4(0,0,0,0);
    xs4[f] = v;
  }
  __syncthreads();
  float acc[8][8];
  #pragma unroll
  for (int r=0;r<8;++r)
    #pragma unroll
    for (int c=0;c<8;++c) acc[r][c] = 0.f;
  int c0 = tid*8;
  for (int k=0;k<CIN;k+=4){
    float4 xv[8];
    #pragma unroll
    for (int r=0;r<8;++r) xv[r] = *(const float4*)&xs[r*CIN+k];
    #pragma unroll
    for (int kk=0;kk<4;++kk){
      float4 w0 = *(const float4*)&w[(size_t)(k+kk)*HC + c0];
      float4 w1 = *(const float4*)&w[(size_t)(k+kk)*HC + c0 + 4];
      float wv[8] = {w0.x,w0.y,w0.z,w0.w,w1.x,w1.y,w1.z,w1.w};
      #pragma unroll
      for (int r=0;r<8;++r){
        float a = ((const float*)&xv[r])[kk];
        #pragma unroll
        for (int c=0;c<8;++c) acc[r][c] = fmaf(a, wv[c], acc[r][c]);
      }
    }
  }
  int head = tid >> 4;
  int cc   = (tid & 15) * 8;
  float asv[8], adv[8];
  #pragma unroll
  for (int c=0;c<8;++c){ asv[c] = as_w[head*COUT + cc + c]; adv[c] = ad_w[head*COUT + cc + c]; }
  #pragma unroll
  for (int r=0;r<8;++r){
    if (r >= rows) break;
    unsigned short vs[8];
    #pragma unroll
    for (int c=0;c<8;++c) vs[c] = f2bf(acc[r][c]);
    *(uint4*)&h2[(size_t)(row0+r)*HC + c0] = *(uint4*)vs;
    float ps = 0.f, pd = 0.f;
    #pragma unroll
    for (int c=0;c<8;++c){ ps = fmaf(acc[r][c], asv[c], ps); pd = fmaf(acc[r][c], adv[c], pd); }
    #pragma unroll
    for (int off=1; off<16; off<<=1){ ps += __shfl_xor(ps, off); pd += __shfl_xor(pd, off); }
    if ((tid & 15) == 0){
      asrc[(size_t)(row0+r)*4 + head] = ps;
      adst[(size_t)(row0+r)*4 + head] = pd;
    }
  }
}

__global__ void k_logits(const int* __restrict__ ei, const float* __restrict__ asrc,
                         const float* __restrict__ adst, float* __restrict__ eo,
                         unsigned* __restrict__ m, int* __restrict__ hist,
                         int E, int ET){
  int e = blockIdx.x*blockDim.x + threadIdx.x;
  if (e >= ET) return;
  int sN = e < E ? ei[e]   : e-E;
  int dN = e < E ? ei[E+e] : e-E;
  atomicAdd(&hist[dN], 1);
  #pragma unroll
  for (int hh=0; hh<4; ++hh){
    float lg = asrc[sN*4+hh] + adst[dN*4+hh];
    lg = lg > 0.f ? lg : NEG_SLOPE*lg;
    eo[(size_t)e*4+hh] = lg;
    atomicMax(&m[dN*4+hh], enc_f(lg));
  }
}

#define STILE 4096
__global__ __launch_bounds__(1024) void k_scan1(const int* __restrict__ in,
                                                int* __restrict__ out,
                                                int* __restrict__ tsum, int n){
  __shared__ int ls[1024];
  int b = blockIdx.x, tid = threadIdx.x;
  int base = b*STILE + tid*4;
  int v[4];
  #pragma unroll
  for (int i=0;i<4;++i){ int idx=base+i; v[i] = idx<n ? in[idx] : 0; }
  int run = v[0]+v[1]+v[2]+v[3];
  ls[tid]=run; __syncthreads();
  for (int off=1; off<1024; off<<=1){
    int t = (tid>=off) ? ls[tid-off] : 0;
    __syncthreads();
    ls[tid]+=t; __syncthreads();
  }
  int excl = ls[tid]-run;
  int sv[4]; sv[0]=excl+v[0]; sv[1]=sv[0]+v[1]; sv[2]=sv[1]+v[2]; sv[3]=sv[2]+v[3];
  #pragma unroll
  for (int i=0;i<4;++i){ int idx=base+i; if (idx<n) out[idx]=sv[i]; }
  if (tid==1023) tsum[b]=ls[1023];
}
__global__ void k_scan2(int* __restrict__ tsum, int T){
  if (threadIdx.x==0 && blockIdx.x==0){
    int off=0;
    for (int t=0;t<T;++t){ int v=tsum[t]; tsum[t]=off; off+=v; }
  }
}
__global__ void k_scan3(const int* __restrict__ scn, const int* __restrict__ toff,
                        int* __restrict__ rowptr, int* __restrict__ cur, int n){
  int i = blockIdx.x*blockDim.x + threadIdx.x;
  if (i<n){
    rowptr[i+1] = scn[i] + toff[i/STILE];
    cur[i] = (i==0) ? 0 : scn[i-1] + toff[(i-1)/STILE];
  }
  if (i==0) rowptr[0] = 0;
}

__global__ void k_expsum(const int* __restrict__ ei, float* __restrict__ eo,
                         const unsigned* __restrict__ m, float* __restrict__ s,
                         int E, int ET){
  int e = blockIdx.x*blockDim.x + threadIdx.x;
  if (e >= ET) return;
  int dN = e < E ? ei[E+e] : e-E;
  #pragma unroll
  for (int hh=0; hh<4; ++hh){
    float ex = expf(eo[(size_t)e*4+hh] - dec_f(m[dN*4+hh]));
    eo[(size_t)e*4+hh] = ex;
    atomicAdd(&s[dN*4+hh], ex);
  }
}

__global__ void k_scatter(const int* __restrict__ ei, int* __restrict__ cur,
                          const float* __restrict__ eo, const float* __restrict__ ssum,
                          int* __restrict__ srcs, float* __restrict__ aw,
                          int E, int ET){
  int e = blockIdx.x*blockDim.x + threadIdx.x;
  if (e >= ET) return;
  int sN = e < E ? ei[e]   : e-E;
  int dN = e < E ? ei[E+e] : e-E;
  int pos = atomicAdd(&cur[dN], 1);
  srcs[pos] = sN;
  float4 ex = *(const float4*)&eo[(size_t)e*4];
  float4 sv = *(const float4*)&ssum[(size_t)dN*4];
  float4 a = make_float4(ex.x/(sv.x+1e-16f), ex.y/(sv.y+1e-16f),
                         ex.z/(sv.z+1e-16f), ex.w/(sv.w+1e-16f));
  *(float4*)&aw[(size_t)pos*4] = a;
}

__global__ __launch_bounds__(256) void k_agg(const int* __restrict__ rowptr,
                                             const int* __restrict__ srcs,
                                             const float* __restrict__ aw,
                                             const unsigned* __restrict__ h2v,
                                             float* __restrict__ agg, int n){
  int d = blockIdx.x, tid = threadIdx.x, head = tid>>6;
  int beg = rowptr[d], end = rowptr[d+1];
  float ax = 0.f, ay = 0.f;
  #pragma unroll 4
  for (int i=beg; i<end; ++i){
    int s   = srcs[i];
    float a = aw[(size_t)i*4 + head];
    unsigned v = h2v[(size_t)s*256 + tid];
    float f0 = __uint_as_float(v << 16);
    float f1 = __uint_as_float(v & 0xffff0000u);
    ax = fmaf(f0, a, ax);
    ay = fmaf(f1, a, ay);
  }
  *(float2*)&agg[(size_t)d*HC + tid*2] = make_float2(ax, ay);
}

// ---- epilogue v2 (fp32 VALU, LDS-staged A and B; kills 16x redundant B reads) ----
// block 128 thr, 32 rows x 128 cols; k-chunks of 32; per-thread 4 rows x 8 cols.
#define KC 32
__global__ __launch_bounds__(128) void k_epi(const float* __restrict__ agg,
                                             const float* __restrict__ gb,
                                             const float* __restrict__ pw,
                                             const float* __restrict__ pb,
                                             const float* __restrict__ x,
                                             const float* __restrict__ lng,
                                             const float* __restrict__ lnb,
                                             float* __restrict__ y, int n){
  __shared__ float As_t[KC*36];      // [k][row(pad36)]  4.6 KB
  __shared__ float Bs[KC*132];       // [k][col(pad132)] 16.9 KB
  int row0 = blockIdx.x*32, tid = threadIdx.x;
  int tc = tid & 15, tr = tid >> 4;          // tc: col-group, tr: row-group
  float acc[4][8];
  #pragma unroll
  for (int r=0;r<4;++r)
    #pragma unroll
    for (int c=0;c<8;++c) acc[r][c] = 0.f;

  for (int kc=0; kc<HC/KC; ++kc){
    // stage A chunk (32 rows x 32 k), fused relu(agg+gb), transposed to [k][row]
    #pragma unroll
    for (int j=0;j<2;++j){
      int f = tid + j*128;           // 0..255 ; r = f>>3, q = f&7 (k-quad)
      int r = f>>3, q = f&7;
      int grow = row0 + r; if (grow >= n) grow = n-1;
      float4 v = *(const float4*)&agg[(size_t)grow*HC + kc*KC + q*4];
      float4 g = *(const float4*)&gb[kc*KC + q*4];
      As_t[(q*4+0)*36 + r] = fmaxf(v.x+g.x, 0.f);
      As_t[(q*4+1)*36 + r] = fmaxf(v.y+g.y, 0.f);
      As_t[(q*4+2)*36 + r] = fmaxf(v.z+g.z, 0.f);
      As_t[(q*4+3)*36 + r] = fmaxf(v.w+g.w, 0.f);
    }
    // stage B chunk (32 k x 128 cols)
    #pragma unroll
    for (int j=0;j<8;++j){
      int f = tid + j*128;           // 0..1023 ; kr = f>>5, c4 = f&31
      int kr = f>>5, c4 = f&31;
      float4 v = *(const float4*)&pw[(size_t)(kc*KC+kr)*COUT + c4*4];
      *(float4*)&Bs[kr*132 + c4*4] = v;
    }
    __syncthreads();
    int r0 = tr*4, c0 = tc*8;
    #pragma unroll 8
    for (int k=0;k<KC;++k){
      float4 av = *(const float4*)&As_t[k*36 + r0];
      float4 b0 = *(const float4*)&Bs[k*132 + c0];
      float4 b1 = *(const float4*)&Bs[k*132 + c0 + 4];
      float bv[8] = {b0.x,b0.y,b0.z,b0.w,b1.x,b1.y,b1.z,b1.w};
      float avv[4] = {av.x,av.y,av.z,av.w};
      #pragma unroll
      for (int r=0;r<4;++r)
        #pragma unroll
        for (int c=0;c<8;++c)
          acc[r][c] = fmaf(avv[r], bv[c], acc[r][c]);
    }
    __syncthreads();
  }

  // LN: thread owns rows tr*4..+3, cols tc*8..+7; 16-lane row reduce.
  int c0 = tc*8;
  #pragma unroll
  for (int rr=0;rr<4;++rr){
    int row = row0 + tr*4 + rr;
    bool live = row < n;
    int rx = live ? row : n-1;
    float v[8]; float sum=0.f, sq=0.f;
    #pragma unroll
    for (int c=0;c<8;++c){
      float t = acc[rr][c] + pb[c0+c] + x[(size_t)rx*COUT + c0 + c];
      v[c]=t; sum+=t; sq = fmaf(t,t,sq);
    }
    #pragma unroll
    for (int off=1; off<16; off<<=1){ sum += __shfl_xor(sum, off); sq += __shfl_xor(sq, off); }
    float mean = sum*(1.f/128.f);
    float var  = sq*(1.f/128.f) - mean*mean;
    float rstd = rsqrtf(var + 1e-5f);
    if (live){
      float o[8];
      #pragma unroll
      for (int c=0;c<8;++c) o[c] = (v[c]-mean)*rstd*lng[c0+c] + lnb[c0+c];
      float* yp = y + (size_t)row*COUT + c0;
      *(float4*)yp     = make_float4(o[0],o[1],o[2],o[3]);
      *(float4*)(yp+4) = make_float4(o[4],o[5],o[6],o[7]);
    }
  }
}

extern "C" void kernel_launch(void* const* d_in, const int* in_sizes, int n_in,
                              void* d_out, int out_size, void* d_ws, size_t ws_size,
                              hipStream_t stream){
  const float* x        = (const float*)d_in[0];
  const int*   ei       = (const int*)  d_in[1];
  const float* lin_w    = (const float*)d_in[2];
  const float* att_src  = (const float*)d_in[3];
  const float* att_dst  = (const float*)d_in[4];
  const float* gat_bias = (const float*)d_in[5];
  const float* proj_w   = (const float*)d_in[6];
  const float* proj_b   = (const float*)d_in[7];
  const float* ln_g     = (const float*)d_in[8];
  const float* ln_b     = (const float*)d_in[9];
  float* y = (float*)d_out;

  int n  = in_sizes[0]/CIN;
  int E  = in_sizes[1]/2;
  int ET = E + n;

  char* p = (char*)d_ws;
  auto alloc = [&](size_t bytes)->char*{
    char* r = p; p += (bytes + 255) & ~(size_t)255; return r;
  };
  unsigned short* h2 = (unsigned short*)alloc((size_t)n*HC*2);
  float*    agg    = (float*)   alloc((size_t)n*HC*4);
  int*      tbl    = (int*)     alloc(16384);
  float*    asrc   = (float*)   alloc((size_t)n*4*4);
  float*    adst   = (float*)   alloc((size_t)n*4*4);
  unsigned* m      = (unsigned*)alloc((size_t)n*4*4);
  float*    ssum   = (float*)   alloc((size_t)n*4*4);
  float*    eo     = (float*)   alloc((size_t)ET*4*4);
  int*      hist   = (int*)     alloc((size_t)n*4);
  int*      scn    = (int*)     alloc((size_t)n*4);
  int*      rowptr = (int*)     alloc((size_t)(n+1)*4);
  int*      cursor = (int*)     alloc((size_t)n*4);
  int*      srcs   = (int*)     alloc((size_t)ET*4);
  float*    aw     = (float*)   alloc((size_t)ET*4*4);
  int T = (n + STILE-1)/STILE;
  int*      tsum   = (int*)     alloc((size_t)T*4);

  k_probe  <<<1, 64, 0, stream>>>(tbl);
  k_init   <<<(4*n+255)/256, 256, 0, stream>>>(m, ssum, hist, n);
  k_lin    <<<(n+7)/8, 64, 0, stream>>>(x, lin_w, att_src, att_dst, h2, asrc, adst, n);
  k_logits <<<(ET+255)/256, 256, 0, stream>>>(ei, asrc, adst, eo, m, hist, E, ET);
  k_scan1  <<<T, 1024, 0, stream>>>(hist, scn, tsum, n);
  k_scan2  <<<1, 64, 0, stream>>>(tsum, T);
  k_scan3  <<<(n+255)/256, 256, 0, stream>>>(scn, tsum, rowptr, cursor, n);
  k_expsum <<<(ET+255)/256, 256, 0, stream>>>(ei, eo, m, ssum, E, ET);
  k_scatter<<<(ET+255)/256, 256, 0, stream>>>(ei, cursor, eo, ssum, srcs, aw, E, ET);
  k_agg    <<<n, 256, 0, stream>>>(rowptr, srcs, aw, (const unsigned*)h2, agg, n);
  k_epi    <<<(n+31)/32, 128, 0, stream>>>(agg, gat_bias, proj_w, proj_b, x, ln_g, ln_b, y, n);

#define LNV(I) k_verdict_##I<<<1, 64, 0, stream>>>(tbl);
  LNV(0) LNV(1) LNV(2) LNV(3) LNV(4) LNV(5) LNV(6) LNV(7)
  LNV(8) LNV(9) LNV(10) LNV(11) LNV(12) LNV(13) LNV(14) LNV(15)
  LNV(16) LNV(17) LNV(18) LNV(19) LNV(20) LNV(21) LNV(22) LNV(23)
  LNV(24) LNV(25) LNV(26) LNV(27) LNV(28) LNV(29) LNV(30) LNV(31)
#undef LNV
}